// Round 17
// baseline (136.707 us; speedup 1.0000x reference)
//
#include <hip/hip_runtime.h>

#define B_ 8
#define C_ 32
#define NI 256   // coarse positions (16x16)
#define C4 8192  // merged channels = 32*256

typedef _Float16 f16;
typedef __attribute__((ext_vector_type(8))) _Float16 f16x8;
typedef __attribute__((ext_vector_type(4))) _Float16 f16x4;
typedef __attribute__((ext_vector_type(2))) _Float16 f16x2;
typedef __attribute__((ext_vector_type(4))) float f32x4;

__device__ __forceinline__ int dh_of(int t) { return (t & 1) | ((t >> 1) & 2) | ((t >> 2) & 4) | ((t >> 3) & 8); }
__device__ __forceinline__ int dw_of(int t) { return ((t >> 1) & 1) | ((t >> 2) & 2) | ((t >> 3) & 4) | ((t >> 4) & 8); }
// xs bank swizzle: permute 16B units within a row (bijective on 0..63)
__device__ __forceinline__ int swzu(int u) { return u ^ ((u >> 3) & 7); }

// async 16B global -> LDS (gfx950). lds must be wave-uniform base; HW adds lane*16.
__device__ __forceinline__ void gld16(const void* g, void* lds) {
  __builtin_amdgcn_global_load_lds(
      (const __attribute__((address_space(1))) unsigned int*)g,
      (__attribute__((address_space(3))) unsigned int*)lds, 16, 0, 0);
}

// ---------------------------------------------------------------------------
// K1a (v5.4): LDS-staged depthwise 3x3 conv + fused Vtt emission. (unchanged)
// ---------------------------------------------------------------------------
__global__ __launch_bounds__(256) void k1a_conv(
    const float* __restrict__ x, const float* __restrict__ wq, const float* __restrict__ bq,
    const float* __restrict__ wk, const float* __restrict__ bk,
    f16* __restrict__ Qn, f16* __restrict__ Kn, f16* __restrict__ Vtt)
{
  __shared__ __align__(16) float xs[19 * 260];   // 19.76 KB
  const int bid = blockIdx.x;
  const int hi = bid & 15, c = (bid >> 4) & 31, b = bid >> 9;
  const int tid = threadIdx.x;
  const size_t cimg = ((size_t)(b * 32 + c)) << 16;

  if (tid < 19) {
    f32x4 z = {};
    *(f32x4*)&xs[tid * 260 + 256] = z;
  }
#pragma unroll
  for (int s = 0; s < 5; ++s) {
    const int idx = tid + 256 * s;
    if (idx < 1152) {
      const int rr = idx >> 6;        // 0..17
      const int col4 = idx & 63;
      const int gh = hi * 16 - 1 + rr;
      f32x4 v = {};
      if ((unsigned)gh < 256u)
        v = *(const f32x4*)(x + cimg + (size_t)gh * 256 + col4 * 4);
      *(f32x4*)&xs[(rr + 1) * 260 + (swzu(col4) << 2)] = v;
    }
  }
  __syncthreads();

  {
    const int hl = tid >> 4, wseg = tid & 15;
    const int w0 = wseg * 16;
    const int ubase = 4 * wseg - 1;
    float q[16], k[16];
    const float bqv = bq[c], bkv = bk[c];
#pragma unroll
    for (int w = 0; w < 16; ++w) { q[w] = bqv; k[w] = bkv; }
#pragma unroll
    for (int dy = 0; dy < 3; ++dy) {
      const float* row = &xs[(hl + 1 + dy) * 260];
      float rbuf[24];
#pragma unroll
      for (int v6 = 0; v6 < 6; ++v6) {
        const int u = ubase + v6;
        const int off = (u < 0) ? -4 : (u >= 64 ? 256 : (swzu(u) << 2));
        const f32x4 a = *(const f32x4*)(row + off);
#pragma unroll
        for (int e = 0; e < 4; ++e) rbuf[v6 * 4 + e] = a[e];
      }
      const float q0 = wq[c * 9 + dy * 3], q1 = wq[c * 9 + dy * 3 + 1], q2 = wq[c * 9 + dy * 3 + 2];
      const float k0 = wk[c * 9 + dy * 3], k1 = wk[c * 9 + dy * 3 + 1], k2 = wk[c * 9 + dy * 3 + 2];
#pragma unroll
      for (int w = 0; w < 16; ++w) {
        q[w] += rbuf[3 + w] * q0 + rbuf[4 + w] * q1 + rbuf[5 + w] * q2;
        k[w] += rbuf[3 + w] * k0 + rbuf[4 + w] * k1 + rbuf[5 + w] * k2;
      }
    }
    f16x8 qo[2], ko[2];
#pragma unroll
    for (int w = 0; w < 16; ++w) { qo[w >> 3][w & 7] = (f16)q[w]; ko[w >> 3][w & 7] = (f16)k[w]; }
    f16* qp = Qn + cimg + (size_t)(hi * 16 + hl) * 256 + w0;
    f16* kp = Kn + cimg + (size_t)(hi * 16 + hl) * 256 + w0;
    *(f16x8*)qp = qo[0]; *(f16x8*)(qp + 8) = qo[1];
    *(f16x8*)kp = ko[0]; *(f16x8*)(kp + 8) = ko[1];
  }

  {  // Vtt[b][t*32+c][hi*16+wi] = xs[dh(t)+2][wi*16+dw(t)] (swizzled word addr)
    const int t = tid;
    const int dh = dh_of(t), dw = dw_of(t);
    const float* rowp = &xs[(dh + 2) * 260];
    f16x8 o0, o1;
#pragma unroll
    for (int wi = 0; wi < 16; ++wi) {
      const int wcol = wi * 16 + dw;
      const f16 v = (f16)rowp[(swzu(wcol >> 2) << 2) | (wcol & 3)];
      if (wi < 8) o0[wi] = v; else o1[wi - 8] = v;
    }
    f16* vdst = Vtt + ((size_t)b * C4 + (size_t)t * 32 + c) * 256 + hi * 16;
    *(f16x8*)vdst = o0;
    *(f16x8*)(vdst + 8) = o1;
  }
}

// ---------------------------------------------------------------------------
// K2 (v3, m97-structure): logits partials from NATURAL layout, LDS-staged.
// Per batch: S[i][j] = sum_k Q[i,k]*K[j,k], k=(c,dh,dw), addr identity:
//   addr(row,k) = c<<16 + (row>>4)<<12 + dh*256 + (row&15)*16 + dw
// Block tile 64i x 128j, BK=64, split-K 8 (grid 512 = 2 blocks/CU).
// Staging: wave's 8-row x 2-half slice = 4 x 256B contiguous chunks.
// ---------------------------------------------------------------------------
__global__ __launch_bounds__(256) void k2_logits(
    const f16* __restrict__ Qn, const f16* __restrict__ Kn, float* __restrict__ Spart)
{
  __shared__ __align__(16) f16 As[64 * 64];    // 8 KB  [i-row][k]
  __shared__ __align__(16) f16 Bs[128 * 64];   // 16 KB [j-row][k]
  const int tile = blockIdx.x;                 // 0..7
  const int mt = tile >> 1, nt = tile & 1;
  const int kz = blockIdx.y, b = blockIdx.z;
  const int i0 = mt * 64, j0 = nt * 128;
  const int tid = threadIdx.x, wave = tid >> 6, lane = tid & 63;
  const int li = lane & 15, lk = lane >> 4;
  const int wm = wave >> 1, wn = wave & 1;     // wave tile 32i x 64j
  const f16* Qb = Qn + ((size_t)b << 21);
  const f16* Kb = Kn + ((size_t)b << 21);
  const int srow = tid >> 3, scol8 = (tid & 7) * 8;

  f32x4 acc[2][4] = {};

  // row-address helper: r = physical matrix row (i or j)
#define K2_RADDR(r) ((((size_t)((r) >> 4)) << 12) + (size_t)((r) & 15) * 16)
#define K2_STAGE(kk)                                                          \
  {                                                                           \
    const int c_ = (kk) >> 8, dhb_ = ((kk) >> 4) & 15;                        \
    const size_t kpart = ((size_t)c_ << 16) +                                 \
        (size_t)(dhb_ + (scol8 >> 4)) * 256 + (scol8 & 8);                    \
    _Pragma("unroll")                                                         \
    for (int j = 0; j < 2; ++j) {                                             \
      const int rg = j * 32 + srow;                                           \
      gld16(Qb + kpart + K2_RADDR(i0 + rg),                                   \
            (char*)As + j * 4096 + wave * 1024);                              \
    }                                                                         \
    _Pragma("unroll")                                                         \
    for (int j = 0; j < 4; ++j) {                                             \
      const int rg = j * 32 + srow;                                           \
      gld16(Kb + kpart + K2_RADDR(j0 + rg),                                   \
            (char*)Bs + j * 4096 + wave * 1024);                              \
    }                                                                         \
  }

  const int kbase = kz * 1024;
  K2_STAGE(kbase);
#pragma unroll
  for (int kt = 0; kt < 16; ++kt) {
    __syncthreads();
#pragma unroll
    for (int kh = 0; kh < 2; ++kh) {
      f16x8 af[2], bf[4];
#pragma unroll
      for (int mi = 0; mi < 2; ++mi)
        af[mi] = *(const f16x8*)&As[(wm * 32 + mi * 16 + li) * 64 + kh * 32 + lk * 8];
#pragma unroll
      for (int ni = 0; ni < 4; ++ni)
        bf[ni] = *(const f16x8*)&Bs[(wn * 64 + ni * 16 + li) * 64 + kh * 32 + lk * 8];
#pragma unroll
      for (int mi = 0; mi < 2; ++mi)
#pragma unroll
        for (int ni = 0; ni < 4; ++ni)
          acc[mi][ni] = __builtin_amdgcn_mfma_f32_16x16x32_f16(af[mi], bf[ni], acc[mi][ni], 0, 0, 0);
    }
    __syncthreads();
    if (kt < 15) K2_STAGE(kbase + (kt + 1) * 64);
  }
#undef K2_STAGE
#undef K2_RADDR

  float* Sp = Spart + ((size_t)kz * B_ + b) * NI * NI;
#pragma unroll
  for (int mi = 0; mi < 2; ++mi)
#pragma unroll
    for (int ni = 0; ni < 4; ++ni)
#pragma unroll
      for (int r = 0; r < 4; ++r) {
        const int ii = i0 + wm * 32 + mi * 16 + lk * 4 + r;
        const int jc = j0 + wn * 64 + ni * 16 + li;
        Sp[(size_t)ii * NI + jc] = acc[mi][ni][r];
      }
}

// ---------------------------------------------------------------------------
// K3: sum 8 partials + softmax over j (256), write f16. One wave per row.
// ---------------------------------------------------------------------------
__global__ __launch_bounds__(256) void k3_softmax(
    const float* __restrict__ Spart, f16* __restrict__ Sh)
{
  const int row = blockIdx.x * 4 + (threadIdx.x >> 6);  // 2048 rows
  const int lane = threadIdx.x & 63;
  const size_t base = (size_t)row * NI + lane * 4;
  f32x4 v = {0.f, 0.f, 0.f, 0.f};
#pragma unroll
  for (int kt = 0; kt < 8; ++kt) {
    const f32x4 p = *(const f32x4*)(Spart + (size_t)kt * B_ * NI * NI + base);
    v[0] += p[0]; v[1] += p[1]; v[2] += p[2]; v[3] += p[3];
  }
  float m = fmaxf(fmaxf(v[0], v[1]), fmaxf(v[2], v[3]));
#pragma unroll
  for (int d = 1; d < 64; d <<= 1) m = fmaxf(m, __shfl_xor(m, d, 64));
  const float e0 = expf(v[0] - m), e1 = expf(v[1] - m), e2 = expf(v[2] - m), e3 = expf(v[3] - m);
  float s = e0 + e1 + e2 + e3;
#pragma unroll
  for (int d = 1; d < 64; d <<= 1) s += __shfl_xor(s, d, 64);
  const float inv = 1.f / s;
  f16x4 o;
  o[0] = (f16)(e0 * inv); o[1] = (f16)(e1 * inv); o[2] = (f16)(e2 * inv); o[3] = (f16)(e3 * inv);
  *(f16x4*)(Sh + (size_t)row * NI + lane * 4) = o;
}

// ---------------------------------------------------------------------------
// K4 (m97-structure + fused residual): per-batch GEMM
// Y[i][c4] = sum_j Vtt[c4][j]*Sh[i][j] + Vtt[c4][i]. (unchanged)
// ---------------------------------------------------------------------------
__global__ __launch_bounds__(256) void k4_ev(
    const f16* __restrict__ Vtt, const f16* __restrict__ Sh, f16* __restrict__ Y)
{
  __shared__ __align__(16) f16 As[128 * 64];  // [m][k] linear, 16 KB
  __shared__ __align__(16) f16 Bs[128 * 64];  // [n][k] linear, 16 KB
  const int mt = blockIdx.x, nt = blockIdx.y, b = blockIdx.z;
  const int m0 = mt * 128, n0 = nt * 128;
  const int tid = threadIdx.x, wave = tid >> 6, lane = tid & 63;
  const int li = lane & 15, lk = lane >> 4;
  const int wm = wave >> 1, wn = wave & 1;
  const f16* Va  = Vtt + (size_t)b * C4 * NI;
  const f16* Shb = Sh + (size_t)b * NI * NI;

  const int srow = tid >> 3, scol = (tid & 7) * 8;

  f32x4 acc[4][4] = {};

#define K4_STAGE(k0)                                                          \
  {                                                                           \
    _Pragma("unroll")                                                         \
    for (int j = 0; j < 4; ++j) {                                             \
      const int rg = j * 32 + srow;                                           \
      gld16(Va + (size_t)(m0 + rg) * NI + (k0) + scol,                        \
            (char*)As + j * 4096 + wave * 1024);                              \
      gld16(Shb + (size_t)(n0 + rg) * NI + (k0) + scol,                       \
            (char*)Bs + j * 4096 + wave * 1024);                              \
    }                                                                         \
  }

  K4_STAGE(0);
#pragma unroll
  for (int kt = 0; kt < 4; ++kt) {
    __syncthreads();
#pragma unroll
    for (int kh = 0; kh < 2; ++kh) {
      f16x8 af[4], bf[4];
#pragma unroll
      for (int mi = 0; mi < 4; ++mi)
        af[mi] = *(const f16x8*)&As[(wm * 64 + mi * 16 + li) * 64 + kh * 32 + lk * 8];
#pragma unroll
      for (int ni = 0; ni < 4; ++ni)
        bf[ni] = *(const f16x8*)&Bs[(wn * 64 + ni * 16 + li) * 64 + kh * 32 + lk * 8];
#pragma unroll
      for (int mi = 0; mi < 4; ++mi)
#pragma unroll
        for (int ni = 0; ni < 4; ++ni)
          acc[mi][ni] = __builtin_amdgcn_mfma_f32_16x16x32_f16(af[mi], bf[ni], acc[mi][ni], 0, 0, 0);
    }
    __syncthreads();
    if (kt < 3) K4_STAGE((kt + 1) * 64);
  }
#undef K4_STAGE

#pragma unroll
  for (int mi = 0; mi < 4; ++mi)
#pragma unroll
    for (int ni = 0; ni < 4; ++ni) {
      const int i = n0 + wn * 64 + ni * 16 + li;
      const int m = m0 + wm * 64 + mi * 16 + lk * 4;
      const f16* vres = Va + (size_t)m * NI + i;   // Vtt[b][m+r][i]
      f16x4 p;
#pragma unroll
      for (int r = 0; r < 4; ++r)
        p[r] = (f16)(acc[mi][ni][r] + (float)vres[(size_t)r * NI]);
      *(f16x4*)(Y + ((size_t)(b * NI + i)) * C4 + m) = p;
    }
}

// ---------------------------------------------------------------------------
// K5: out[b,o,h,w] = sum_ci w1[o,ci] * Y[b, i(h,w), t(h,w)*32+ci], fp32.
// (unchanged)
// ---------------------------------------------------------------------------
__global__ __launch_bounds__(256) void k5_w1_unpermute(
    const f16* __restrict__ Y, const float* __restrict__ w1, float* __restrict__ out)
{
  __shared__ f16 w1s[32 * 32];
  const int bid = blockIdx.x;
  const int b = bid >> 8, i = bid & 255;
  const int hi = i >> 4, wi = i & 15;
  const int tid = threadIdx.x;
#pragma unroll
  for (int e = 0; e < 4; ++e) w1s[tid + 256 * e] = (f16)w1[tid + 256 * e];
  __syncthreads();

  const int wave = tid >> 6, lane = tid & 63, li = lane & 15, lk = lane >> 4;
  const f16* Yrow = Y + ((size_t)(b * NI + i)) * C4;
  const f16x8 b0 = *(const f16x8*)(&w1s[li * 32 + lk * 8]);         // o = li
  const f16x8 b1 = *(const f16x8*)(&w1s[(16 + li) * 32 + lk * 8]);  // o = 16+li

#pragma unroll
  for (int q = 0; q < 4; ++q) {
    const int tt = wave * 4 + q;
    const f16x8 a = *(const f16x8*)(Yrow + (size_t)(tt * 16 + li) * 32 + lk * 8);
    f32x4 d0 = {}, d1 = {};
    d0 = __builtin_amdgcn_mfma_f32_16x16x32_f16(a, b0, d0, 0, 0, 0);
    d1 = __builtin_amdgcn_mfma_f32_16x16x32_f16(a, b1, d1, 0, 0, 0);
#pragma unroll
    for (int r = 0; r < 4; ++r) {
      const int t = tt * 16 + lk * 4 + r;
      const int dh = dh_of(t), dw = dw_of(t);
      const int h = hi * 16 + dh, w = wi * 16 + dw;
      out[(((size_t)(b * 32 + li)) * 256 + h) * 256 + w] = d0[r];
      out[(((size_t)(b * 32 + 16 + li)) * 256 + h) * 256 + w] = d1[r];
    }
  }
}

// ---------------------------------------------------------------------------
extern "C" void kernel_launch(void* const* d_in, const int* in_sizes, int n_in,
                              void* d_out, int out_size, void* d_ws, size_t ws_size,
                              hipStream_t stream)
{
  const float* x  = (const float*)d_in[0];
  const float* wq = (const float*)d_in[1];
  const float* bq = (const float*)d_in[2];
  const float* wk = (const float*)d_in[3];
  const float* bk = (const float*)d_in[4];
  const float* w1 = (const float*)d_in[5];
  float* out = (float*)d_out;
  char* ws = (char*)d_ws;

  // ws: Qn [0,32M) | Kn [32M,64M) | Vtt [64M,96M) | Spart [96M,112M) | Sh [112M,113M)
  // Y aliases Qn (dead after K2). (ws >= 137MB established round 12.)
  f16*   Qn    = (f16*)(ws);
  f16*   Kn    = (f16*)(ws + 33554432);
  f16*   Vtt   = (f16*)(ws + 67108864);
  float* Spart = (float*)(ws + 100663296);
  f16*   Sh    = (f16*)(ws + 117440512);
  f16*   Y     = Qn;

  k1a_conv<<<4096, 256, 0, stream>>>(x, wq, bq, wk, bk, Qn, Kn, Vtt);
  k2_logits<<<dim3(8, 8, 8), 256, 0, stream>>>(Qn, Kn, Spart);
  k3_softmax<<<512, 256, 0, stream>>>(Spart, Sh);
  k4_ev<<<dim3(64, 2, 8), 256, 0, stream>>>(Vtt, Sh, Y);
  k5_w1_unpermute<<<2048, 256, 0, stream>>>(Y, w1, out);
}

// Round 19
// 133.817 us; speedup vs baseline: 1.0216x; 1.0216x over previous
//
#include <hip/hip_runtime.h>

#define B_ 8
#define C_ 32
#define NI 256   // coarse positions (16x16)
#define C4 8192  // merged channels = 32*256

typedef _Float16 f16;
typedef __attribute__((ext_vector_type(8))) _Float16 f16x8;
typedef __attribute__((ext_vector_type(4))) _Float16 f16x4;
typedef __attribute__((ext_vector_type(2))) _Float16 f16x2;
typedef __attribute__((ext_vector_type(4))) float f32x4;

__device__ __forceinline__ int dh_of(int t) { return (t & 1) | ((t >> 1) & 2) | ((t >> 2) & 4) | ((t >> 3) & 8); }
__device__ __forceinline__ int dw_of(int t) { return ((t >> 1) & 1) | ((t >> 2) & 2) | ((t >> 3) & 4) | ((t >> 4) & 8); }

// async 16B global -> LDS (gfx950). lds must be wave-uniform base; HW adds lane*16.
__device__ __forceinline__ void gld16(const void* g, void* lds) {
  __builtin_amdgcn_global_load_lds(
      (const __attribute__((address_space(1))) unsigned int*)g,
      (__attribute__((address_space(3))) unsigned int*)lds, 16, 0, 0);
}

// ---------------------------------------------------------------------------
// K1a (v6.1): LDS-staged depthwise 3x3 conv + fused Vtt emission.
// Async global_load_lds staging; ROUND-19 FIX: restore the v5 row mapping --
// strip row rr (gh = hi*16-1+rr, rr=0..17) lands in LDS ROW rr+1 (round 18
// staged into row rr, shifting all conv/Vtt reads by one image row ->
// absmax 8.9). LDS row 0 stays pad-only (halo source for conv row 1).
// ---------------------------------------------------------------------------
__global__ __launch_bounds__(256) void k1a_conv(
    const float* __restrict__ x, const float* __restrict__ wq, const float* __restrict__ bq,
    const float* __restrict__ wk, const float* __restrict__ bk,
    f16* __restrict__ Qn, f16* __restrict__ Kn, f16* __restrict__ Vtt)
{
  __shared__ __align__(16) float xs[19 * 260];   // 19.76 KB
  const int bid = blockIdx.x;
  const int hi = bid & 15, c = (bid >> 4) & 31, b = bid >> 9;
  const int tid = threadIdx.x, wave = tid >> 6, lane = tid & 63;
  const size_t cimg = ((size_t)(b * 32 + c)) << 16;

  // zero the 4-word pad of every row (halo source)
  if (tid < 19) {
    f32x4 z = {};
    *(f32x4*)&xs[tid * 260 + 256] = z;
  }
  // async stage: strip row rr -> LDS row rr+1; wave w handles rr = w, w+4, ...
  for (int rr = wave; rr < 18; rr += 4) {
    const int gh = hi * 16 - 1 + rr;
    if ((unsigned)gh < 256u) {
      gld16(x + cimg + (size_t)gh * 256 + lane * 4, (char*)&xs[(rr + 1) * 260]);
    } else {
      f32x4 z = {};
      *(f32x4*)&xs[(rr + 1) * 260 + lane * 4] = z;
    }
  }
  __syncthreads();

  // Q/K conv: thread = (hl = tid>>4, wseg = tid&15), 16 outputs along w
  {
    const int hl = tid >> 4, wseg = tid & 15;
    const int w0 = wseg * 16;
    float q[16], k[16];
    const float bqv = bq[c], bkv = bk[c];
#pragma unroll
    for (int w = 0; w < 16; ++w) { q[w] = bqv; k[w] = bkv; }
#pragma unroll
    for (int dy = 0; dy < 3; ++dy) {
      const float* row = &xs[(hl + 1 + dy) * 260];
      float rbuf[24];   // cols w0-4 .. w0+19 (aligned b128 x6; pads supply halo)
#pragma unroll
      for (int v6 = 0; v6 < 6; ++v6) {
        const f32x4 a = *(const f32x4*)(row + w0 - 4 + 4 * v6);
#pragma unroll
        for (int e = 0; e < 4; ++e) rbuf[v6 * 4 + e] = a[e];
      }
      const float q0 = wq[c * 9 + dy * 3], q1 = wq[c * 9 + dy * 3 + 1], q2 = wq[c * 9 + dy * 3 + 2];
      const float k0 = wk[c * 9 + dy * 3], k1 = wk[c * 9 + dy * 3 + 1], k2 = wk[c * 9 + dy * 3 + 2];
#pragma unroll
      for (int w = 0; w < 16; ++w) {   // col w0+w-1 = rbuf[3+w]
        q[w] += rbuf[3 + w] * q0 + rbuf[4 + w] * q1 + rbuf[5 + w] * q2;
        k[w] += rbuf[3 + w] * k0 + rbuf[4 + w] * k1 + rbuf[5 + w] * k2;
      }
    }
    f16x8 qo[2], ko[2];
#pragma unroll
    for (int w = 0; w < 16; ++w) { qo[w >> 3][w & 7] = (f16)q[w]; ko[w >> 3][w & 7] = (f16)k[w]; }
    f16* qp = Qn + cimg + (size_t)(hi * 16 + hl) * 256 + w0;
    f16* kp = Kn + cimg + (size_t)(hi * 16 + hl) * 256 + w0;
    *(f16x8*)qp = qo[0]; *(f16x8*)(qp + 8) = qo[1];
    *(f16x8*)kp = ko[0]; *(f16x8*)(kp + 8) = ko[1];
  }

  {  // Vtt[b][t*32+c][hi*16+wi] = xs[dh(t)+2][wi*16+dw(t)]
    const int t = tid;
    const int dh = dh_of(t), dw = dw_of(t);
    const float* rowp = &xs[(dh + 2) * 260];
    f16x8 o0, o1;
#pragma unroll
    for (int wi = 0; wi < 16; ++wi) {
      const f16 v = (f16)rowp[wi * 16 + dw];
      if (wi < 8) o0[wi] = v; else o1[wi - 8] = v;
    }
    f16* vdst = Vtt + ((size_t)b * C4 + (size_t)t * 32 + c) * 256 + hi * 16;
    *(f16x8*)vdst = o0;
    *(f16x8*)(vdst + 8) = o1;
  }
}

// ---------------------------------------------------------------------------
// K2 (m97-structure): logits partials from NATURAL layout, LDS-staged.
// Block tile 64i x 128j, BK=64, split-K 8 (grid 512 = 2 blocks/CU).
// ---------------------------------------------------------------------------
__global__ __launch_bounds__(256) void k2_logits(
    const f16* __restrict__ Qn, const f16* __restrict__ Kn, float* __restrict__ Spart)
{
  __shared__ __align__(16) f16 As[64 * 64];    // 8 KB  [i-row][k]
  __shared__ __align__(16) f16 Bs[128 * 64];   // 16 KB [j-row][k]
  const int tile = blockIdx.x;                 // 0..7
  const int mt = tile >> 1, nt = tile & 1;
  const int kz = blockIdx.y, b = blockIdx.z;
  const int i0 = mt * 64, j0 = nt * 128;
  const int tid = threadIdx.x, wave = tid >> 6, lane = tid & 63;
  const int li = lane & 15, lk = lane >> 4;
  const int wm = wave >> 1, wn = wave & 1;     // wave tile 32i x 64j
  const f16* Qb = Qn + ((size_t)b << 21);
  const f16* Kb = Kn + ((size_t)b << 21);
  const int srow = tid >> 3, scol8 = (tid & 7) * 8;

  f32x4 acc[2][4] = {};

#define K2_RADDR(r) ((((size_t)((r) >> 4)) << 12) + (size_t)((r) & 15) * 16)
#define K2_STAGE(kk)                                                          \
  {                                                                           \
    const int c_ = (kk) >> 8, dhb_ = ((kk) >> 4) & 15;                        \
    const size_t kpart = ((size_t)c_ << 16) +                                 \
        (size_t)(dhb_ + (scol8 >> 4)) * 256 + (scol8 & 8);                    \
    _Pragma("unroll")                                                         \
    for (int j = 0; j < 2; ++j) {                                             \
      const int rg = j * 32 + srow;                                           \
      gld16(Qb + kpart + K2_RADDR(i0 + rg),                                   \
            (char*)As + j * 4096 + wave * 1024);                              \
    }                                                                         \
    _Pragma("unroll")                                                         \
    for (int j = 0; j < 4; ++j) {                                             \
      const int rg = j * 32 + srow;                                           \
      gld16(Kb + kpart + K2_RADDR(j0 + rg),                                   \
            (char*)Bs + j * 4096 + wave * 1024);                              \
    }                                                                         \
  }

  const int kbase = kz * 1024;
  K2_STAGE(kbase);
#pragma unroll
  for (int kt = 0; kt < 16; ++kt) {
    __syncthreads();
#pragma unroll
    for (int kh = 0; kh < 2; ++kh) {
      f16x8 af[2], bf[4];
#pragma unroll
      for (int mi = 0; mi < 2; ++mi)
        af[mi] = *(const f16x8*)&As[(wm * 32 + mi * 16 + li) * 64 + kh * 32 + lk * 8];
#pragma unroll
      for (int ni = 0; ni < 4; ++ni)
        bf[ni] = *(const f16x8*)&Bs[(wn * 64 + ni * 16 + li) * 64 + kh * 32 + lk * 8];
#pragma unroll
      for (int mi = 0; mi < 2; ++mi)
#pragma unroll
        for (int ni = 0; ni < 4; ++ni)
          acc[mi][ni] = __builtin_amdgcn_mfma_f32_16x16x32_f16(af[mi], bf[ni], acc[mi][ni], 0, 0, 0);
    }
    __syncthreads();
    if (kt < 15) K2_STAGE(kbase + (kt + 1) * 64);
  }
#undef K2_STAGE
#undef K2_RADDR

  float* Sp = Spart + ((size_t)kz * B_ + b) * NI * NI;
#pragma unroll
  for (int mi = 0; mi < 2; ++mi)
#pragma unroll
    for (int ni = 0; ni < 4; ++ni)
#pragma unroll
      for (int r = 0; r < 4; ++r) {
        const int ii = i0 + wm * 32 + mi * 16 + lk * 4 + r;
        const int jc = j0 + wn * 64 + ni * 16 + li;
        Sp[(size_t)ii * NI + jc] = acc[mi][ni][r];
      }
}

// ---------------------------------------------------------------------------
// K3: sum 8 partials + softmax over j (256), write f16. One wave per row.
// ---------------------------------------------------------------------------
__global__ __launch_bounds__(256) void k3_softmax(
    const float* __restrict__ Spart, f16* __restrict__ Sh)
{
  const int row = blockIdx.x * 4 + (threadIdx.x >> 6);  // 2048 rows
  const int lane = threadIdx.x & 63;
  const size_t base = (size_t)row * NI + lane * 4;
  f32x4 v = {0.f, 0.f, 0.f, 0.f};
#pragma unroll
  for (int kt = 0; kt < 8; ++kt) {
    const f32x4 p = *(const f32x4*)(Spart + (size_t)kt * B_ * NI * NI + base);
    v[0] += p[0]; v[1] += p[1]; v[2] += p[2]; v[3] += p[3];
  }
  float m = fmaxf(fmaxf(v[0], v[1]), fmaxf(v[2], v[3]));
#pragma unroll
  for (int d = 1; d < 64; d <<= 1) m = fmaxf(m, __shfl_xor(m, d, 64));
  const float e0 = expf(v[0] - m), e1 = expf(v[1] - m), e2 = expf(v[2] - m), e3 = expf(v[3] - m);
  float s = e0 + e1 + e2 + e3;
#pragma unroll
  for (int d = 1; d < 64; d <<= 1) s += __shfl_xor(s, d, 64);
  const float inv = 1.f / s;
  f16x4 o;
  o[0] = (f16)(e0 * inv); o[1] = (f16)(e1 * inv); o[2] = (f16)(e2 * inv); o[3] = (f16)(e3 * inv);
  *(f16x4*)(Sh + (size_t)row * NI + lane * 4) = o;
}

// ---------------------------------------------------------------------------
// K4 (m97-structure + fused residual): per-batch GEMM
// Y[i][c4] = sum_j Vtt[c4][j]*Sh[i][j] + Vtt[c4][i]. (unchanged)
// ---------------------------------------------------------------------------
__global__ __launch_bounds__(256) void k4_ev(
    const f16* __restrict__ Vtt, const f16* __restrict__ Sh, f16* __restrict__ Y)
{
  __shared__ __align__(16) f16 As[128 * 64];  // [m][k] linear, 16 KB
  __shared__ __align__(16) f16 Bs[128 * 64];  // [n][k] linear, 16 KB
  const int mt = blockIdx.x, nt = blockIdx.y, b = blockIdx.z;
  const int m0 = mt * 128, n0 = nt * 128;
  const int tid = threadIdx.x, wave = tid >> 6, lane = tid & 63;
  const int li = lane & 15, lk = lane >> 4;
  const int wm = wave >> 1, wn = wave & 1;
  const f16* Va  = Vtt + (size_t)b * C4 * NI;
  const f16* Shb = Sh + (size_t)b * NI * NI;

  const int srow = tid >> 3, scol = (tid & 7) * 8;

  f32x4 acc[4][4] = {};

#define K4_STAGE(k0)                                                          \
  {                                                                           \
    _Pragma("unroll")                                                         \
    for (int j = 0; j < 4; ++j) {                                             \
      const int rg = j * 32 + srow;                                           \
      gld16(Va + (size_t)(m0 + rg) * NI + (k0) + scol,                        \
            (char*)As + j * 4096 + wave * 1024);                              \
      gld16(Shb + (size_t)(n0 + rg) * NI + (k0) + scol,                       \
            (char*)Bs + j * 4096 + wave * 1024);                              \
    }                                                                         \
  }

  K4_STAGE(0);
#pragma unroll
  for (int kt = 0; kt < 4; ++kt) {
    __syncthreads();
#pragma unroll
    for (int kh = 0; kh < 2; ++kh) {
      f16x8 af[4], bf[4];
#pragma unroll
      for (int mi = 0; mi < 4; ++mi)
        af[mi] = *(const f16x8*)&As[(wm * 64 + mi * 16 + li) * 64 + kh * 32 + lk * 8];
#pragma unroll
      for (int ni = 0; ni < 4; ++ni)
        bf[ni] = *(const f16x8*)&Bs[(wn * 64 + ni * 16 + li) * 64 + kh * 32 + lk * 8];
#pragma unroll
      for (int mi = 0; mi < 4; ++mi)
#pragma unroll
        for (int ni = 0; ni < 4; ++ni)
          acc[mi][ni] = __builtin_amdgcn_mfma_f32_16x16x32_f16(af[mi], bf[ni], acc[mi][ni], 0, 0, 0);
    }
    __syncthreads();
    if (kt < 3) K4_STAGE((kt + 1) * 64);
  }
#undef K4_STAGE

#pragma unroll
  for (int mi = 0; mi < 4; ++mi)
#pragma unroll
    for (int ni = 0; ni < 4; ++ni) {
      const int i = n0 + wn * 64 + ni * 16 + li;
      const int m = m0 + wm * 64 + mi * 16 + lk * 4;
      const f16* vres = Va + (size_t)m * NI + i;   // Vtt[b][m+r][i]
      f16x4 p;
#pragma unroll
      for (int r = 0; r < 4; ++r)
        p[r] = (f16)(acc[mi][ni][r] + (float)vres[(size_t)r * NI]);
      *(f16x4*)(Y + ((size_t)(b * NI + i)) * C4 + m) = p;
    }
}

// ---------------------------------------------------------------------------
// K5: out[b,o,h,w] = sum_ci w1[o,ci] * Y[b, i(h,w), t(h,w)*32+ci], fp32.
// (unchanged)
// ---------------------------------------------------------------------------
__global__ __launch_bounds__(256) void k5_w1_unpermute(
    const f16* __restrict__ Y, const float* __restrict__ w1, float* __restrict__ out)
{
  __shared__ f16 w1s[32 * 32];
  const int bid = blockIdx.x;
  const int b = bid >> 8, i = bid & 255;
  const int hi = i >> 4, wi = i & 15;
  const int tid = threadIdx.x;
#pragma unroll
  for (int e = 0; e < 4; ++e) w1s[tid + 256 * e] = (f16)w1[tid + 256 * e];
  __syncthreads();

  const int wave = tid >> 6, lane = tid & 63, li = lane & 15, lk = lane >> 4;
  const f16* Yrow = Y + ((size_t)(b * NI + i)) * C4;
  const f16x8 b0 = *(const f16x8*)(&w1s[li * 32 + lk * 8]);         // o = li
  const f16x8 b1 = *(const f16x8*)(&w1s[(16 + li) * 32 + lk * 8]);  // o = 16+li

#pragma unroll
  for (int q = 0; q < 4; ++q) {
    const int tt = wave * 4 + q;
    const f16x8 a = *(const f16x8*)(Yrow + (size_t)(tt * 16 + li) * 32 + lk * 8);
    f32x4 d0 = {}, d1 = {};
    d0 = __builtin_amdgcn_mfma_f32_16x16x32_f16(a, b0, d0, 0, 0, 0);
    d1 = __builtin_amdgcn_mfma_f32_16x16x32_f16(a, b1, d1, 0, 0, 0);
#pragma unroll
    for (int r = 0; r < 4; ++r) {
      const int t = tt * 16 + lk * 4 + r;
      const int dh = dh_of(t), dw = dw_of(t);
      const int h = hi * 16 + dh, w = wi * 16 + dw;
      out[(((size_t)(b * 32 + li)) * 256 + h) * 256 + w] = d0[r];
      out[(((size_t)(b * 32 + 16 + li)) * 256 + h) * 256 + w] = d1[r];
    }
  }
}

// ---------------------------------------------------------------------------
extern "C" void kernel_launch(void* const* d_in, const int* in_sizes, int n_in,
                              void* d_out, int out_size, void* d_ws, size_t ws_size,
                              hipStream_t stream)
{
  const float* x  = (const float*)d_in[0];
  const float* wq = (const float*)d_in[1];
  const float* bq = (const float*)d_in[2];
  const float* wk = (const float*)d_in[3];
  const float* bk = (const float*)d_in[4];
  const float* w1 = (const float*)d_in[5];
  float* out = (float*)d_out;
  char* ws = (char*)d_ws;

  // ws: Qn [0,32M) | Kn [32M,64M) | Vtt [64M,96M) | Spart [96M,112M) | Sh [112M,113M)
  // Y aliases Qn (dead after K2).
  f16*   Qn    = (f16*)(ws);
  f16*   Kn    = (f16*)(ws + 33554432);
  f16*   Vtt   = (f16*)(ws + 67108864);
  float* Spart = (float*)(ws + 100663296);
  f16*   Sh    = (f16*)(ws + 117440512);
  f16*   Y     = Qn;

  k1a_conv<<<4096, 256, 0, stream>>>(x, wq, bq, wk, bk, Qn, Kn, Vtt);
  k2_logits<<<dim3(8, 8, 8), 256, 0, stream>>>(Qn, Kn, Spart);
  k3_softmax<<<512, 256, 0, stream>>>(Spart, Sh);
  k4_ev<<<dim3(64, 2, 8), 256, 0, stream>>>(Vtt, Sh, Y);
  k5_w1_unpermute<<<2048, 256, 0, stream>>>(Y, w1, out);
}

// Round 20
// 132.690 us; speedup vs baseline: 1.0303x; 1.0085x over previous
//
#include <hip/hip_runtime.h>

#define B_ 8
#define C_ 32
#define NI 256   // coarse positions (16x16)
#define C4 8192  // merged channels = 32*256

typedef _Float16 f16;
typedef __attribute__((ext_vector_type(8))) _Float16 f16x8;
typedef __attribute__((ext_vector_type(4))) _Float16 f16x4;
typedef __attribute__((ext_vector_type(2))) _Float16 f16x2;
typedef __attribute__((ext_vector_type(4))) float f32x4;

__device__ __forceinline__ int dh_of(int t) { return (t & 1) | ((t >> 1) & 2) | ((t >> 2) & 4) | ((t >> 3) & 8); }
__device__ __forceinline__ int dw_of(int t) { return ((t >> 1) & 1) | ((t >> 2) & 2) | ((t >> 3) & 4) | ((t >> 4) & 8); }

// async 16B global -> LDS (gfx950). lds must be wave-uniform base; HW adds lane*16.
__device__ __forceinline__ void gld16(const void* g, void* lds) {
  __builtin_amdgcn_global_load_lds(
      (const __attribute__((address_space(1))) unsigned int*)g,
      (__attribute__((address_space(3))) unsigned int*)lds, 16, 0, 0);
}

// ---------------------------------------------------------------------------
// K1a (v7): software-pipelined LDS-staged conv. block = (b, c, 64-row quarter),
// 4 strips of 16 rows, DOUBLE-BUFFERED: [bar][issue stage(s+1) async][compute s]
// -- stage(s+1)'s gld16s fly during compute(s), so the next barrier's vmcnt
// drain finds them landed (K4's 2-phase loop applied to the conv; rounds
// 12-19: every serial stage->drain->compute variant stuck at 50-56us with
// nothing saturated = exposed HBM latency). 39.5KB LDS -> 4 blocks/CU;
// grid 1024 = one generation, no tail. Strip row rr -> LDS row rr+1
// (row 0 = pad-only halo source; round-18 lesson: propagate this mapping!).
// ---------------------------------------------------------------------------
__global__ __launch_bounds__(256) void k1a_conv(
    const float* __restrict__ x, const float* __restrict__ wq, const float* __restrict__ bq,
    const float* __restrict__ wk, const float* __restrict__ bk,
    f16* __restrict__ Qn, f16* __restrict__ Kn, f16* __restrict__ Vtt)
{
  __shared__ __align__(16) float xs[2][19 * 260];   // 39.5 KB
  const int bid = blockIdx.x;
  const int hq = bid & 3, c = (bid >> 2) & 31, b = bid >> 7;
  const int tid = threadIdx.x, wave = tid >> 6, lane = tid & 63;
  const size_t cimg = ((size_t)(b * 32 + c)) << 16;

  // zero the 4-word pad of every row in both buffers (halo source)
  if (tid < 38) {
    const int bsel = tid >= 19, r = tid - bsel * 19;
    f32x4 z = {};
    *(f32x4*)&xs[bsel][r * 260 + 256] = z;
  }

#define K1_STAGE(s)                                                           \
  {                                                                           \
    float* buf_ = xs[(s) & 1];                                                \
    for (int rr = wave; rr < 18; rr += 4) {                                   \
      const int gh = hq * 64 + (s) * 16 - 1 + rr;                             \
      if ((unsigned)gh < 256u) {                                              \
        gld16(x + cimg + (size_t)gh * 256 + lane * 4,                         \
              (char*)&buf_[(rr + 1) * 260]);                                  \
      } else {                                                                \
        f32x4 z_ = {};                                                        \
        *(f32x4*)&buf_[(rr + 1) * 260 + lane * 4] = z_;                       \
      }                                                                       \
    }                                                                         \
  }

  K1_STAGE(0);
#pragma unroll
  for (int s = 0; s < 4; ++s) {
    __syncthreads();              // drains stage(s); compute(s-1) done
    if (s < 3) K1_STAGE(s + 1);   // issued now, lands during compute(s)
    const float* bufp = xs[s & 1];
    const int hi = hq * 4 + s;

    // Q/K conv: thread = (hl = tid>>4, wseg = tid&15), 16 outputs along w
    {
      const int hl = tid >> 4, wseg = tid & 15;
      const int w0 = wseg * 16;
      float q[16], k[16];
      const float bqv = bq[c], bkv = bk[c];
#pragma unroll
      for (int w = 0; w < 16; ++w) { q[w] = bqv; k[w] = bkv; }
#pragma unroll
      for (int dy = 0; dy < 3; ++dy) {
        const float* row = &bufp[(hl + 1 + dy) * 260];
        float rbuf[24];   // cols w0-4 .. w0+19 (aligned b128 x6; pads supply halo)
#pragma unroll
        for (int v6 = 0; v6 < 6; ++v6) {
          const f32x4 a = *(const f32x4*)(row + w0 - 4 + 4 * v6);
#pragma unroll
          for (int e = 0; e < 4; ++e) rbuf[v6 * 4 + e] = a[e];
        }
        const float q0 = wq[c * 9 + dy * 3], q1 = wq[c * 9 + dy * 3 + 1], q2 = wq[c * 9 + dy * 3 + 2];
        const float k0 = wk[c * 9 + dy * 3], k1 = wk[c * 9 + dy * 3 + 1], k2 = wk[c * 9 + dy * 3 + 2];
#pragma unroll
        for (int w = 0; w < 16; ++w) {   // col w0+w-1 = rbuf[3+w]
          q[w] += rbuf[3 + w] * q0 + rbuf[4 + w] * q1 + rbuf[5 + w] * q2;
          k[w] += rbuf[3 + w] * k0 + rbuf[4 + w] * k1 + rbuf[5 + w] * k2;
        }
      }
      f16x8 qo[2], ko[2];
#pragma unroll
      for (int w = 0; w < 16; ++w) { qo[w >> 3][w & 7] = (f16)q[w]; ko[w >> 3][w & 7] = (f16)k[w]; }
      f16* qp = Qn + cimg + (size_t)(hi * 16 + hl) * 256 + w0;
      f16* kp = Kn + cimg + (size_t)(hi * 16 + hl) * 256 + w0;
      *(f16x8*)qp = qo[0]; *(f16x8*)(qp + 8) = qo[1];
      *(f16x8*)kp = ko[0]; *(f16x8*)(kp + 8) = ko[1];
    }

    {  // Vtt[b][t*32+c][hi*16+wi] = buf[dh(t)+2][wi*16+dw(t)]
      const int t = tid;
      const int dh = dh_of(t), dw = dw_of(t);
      const float* rowp = &bufp[(dh + 2) * 260];
      f16x8 o0, o1;
#pragma unroll
      for (int wi = 0; wi < 16; ++wi) {
        const f16 v = (f16)rowp[wi * 16 + dw];
        if (wi < 8) o0[wi] = v; else o1[wi - 8] = v;
      }
      f16* vdst = Vtt + ((size_t)b * C4 + (size_t)t * 32 + c) * 256 + hi * 16;
      *(f16x8*)vdst = o0;
      *(f16x8*)(vdst + 8) = o1;
    }
  }
#undef K1_STAGE
}

// ---------------------------------------------------------------------------
// K2 (m97-structure): logits partials from NATURAL layout, LDS-staged.
// Block tile 64i x 128j, BK=64, split-K 8 (grid 512 = 2 blocks/CU).
// ---------------------------------------------------------------------------
__global__ __launch_bounds__(256) void k2_logits(
    const f16* __restrict__ Qn, const f16* __restrict__ Kn, float* __restrict__ Spart)
{
  __shared__ __align__(16) f16 As[64 * 64];    // 8 KB  [i-row][k]
  __shared__ __align__(16) f16 Bs[128 * 64];   // 16 KB [j-row][k]
  const int tile = blockIdx.x;                 // 0..7
  const int mt = tile >> 1, nt = tile & 1;
  const int kz = blockIdx.y, b = blockIdx.z;
  const int i0 = mt * 64, j0 = nt * 128;
  const int tid = threadIdx.x, wave = tid >> 6, lane = tid & 63;
  const int li = lane & 15, lk = lane >> 4;
  const int wm = wave >> 1, wn = wave & 1;     // wave tile 32i x 64j
  const f16* Qb = Qn + ((size_t)b << 21);
  const f16* Kb = Kn + ((size_t)b << 21);
  const int srow = tid >> 3, scol8 = (tid & 7) * 8;

  f32x4 acc[2][4] = {};

#define K2_RADDR(r) ((((size_t)((r) >> 4)) << 12) + (size_t)((r) & 15) * 16)
#define K2_STAGE(kk)                                                          \
  {                                                                           \
    const int c_ = (kk) >> 8, dhb_ = ((kk) >> 4) & 15;                        \
    const size_t kpart = ((size_t)c_ << 16) +                                 \
        (size_t)(dhb_ + (scol8 >> 4)) * 256 + (scol8 & 8);                    \
    _Pragma("unroll")                                                         \
    for (int j = 0; j < 2; ++j) {                                             \
      const int rg = j * 32 + srow;                                           \
      gld16(Qb + kpart + K2_RADDR(i0 + rg),                                   \
            (char*)As + j * 4096 + wave * 1024);                              \
    }                                                                         \
    _Pragma("unroll")                                                         \
    for (int j = 0; j < 4; ++j) {                                             \
      const int rg = j * 32 + srow;                                           \
      gld16(Kb + kpart + K2_RADDR(j0 + rg),                                   \
            (char*)Bs + j * 4096 + wave * 1024);                              \
    }                                                                         \
  }

  const int kbase = kz * 1024;
  K2_STAGE(kbase);
#pragma unroll
  for (int kt = 0; kt < 16; ++kt) {
    __syncthreads();
#pragma unroll
    for (int kh = 0; kh < 2; ++kh) {
      f16x8 af[2], bf[4];
#pragma unroll
      for (int mi = 0; mi < 2; ++mi)
        af[mi] = *(const f16x8*)&As[(wm * 32 + mi * 16 + li) * 64 + kh * 32 + lk * 8];
#pragma unroll
      for (int ni = 0; ni < 4; ++ni)
        bf[ni] = *(const f16x8*)&Bs[(wn * 64 + ni * 16 + li) * 64 + kh * 32 + lk * 8];
#pragma unroll
      for (int mi = 0; mi < 2; ++mi)
#pragma unroll
        for (int ni = 0; ni < 4; ++ni)
          acc[mi][ni] = __builtin_amdgcn_mfma_f32_16x16x32_f16(af[mi], bf[ni], acc[mi][ni], 0, 0, 0);
    }
    __syncthreads();
    if (kt < 15) K2_STAGE(kbase + (kt + 1) * 64);
  }
#undef K2_STAGE
#undef K2_RADDR

  float* Sp = Spart + ((size_t)kz * B_ + b) * NI * NI;
#pragma unroll
  for (int mi = 0; mi < 2; ++mi)
#pragma unroll
    for (int ni = 0; ni < 4; ++ni)
#pragma unroll
      for (int r = 0; r < 4; ++r) {
        const int ii = i0 + wm * 32 + mi * 16 + lk * 4 + r;
        const int jc = j0 + wn * 64 + ni * 16 + li;
        Sp[(size_t)ii * NI + jc] = acc[mi][ni][r];
      }
}

// ---------------------------------------------------------------------------
// K3: sum 8 partials + softmax over j (256), write f16. One wave per row.
// ---------------------------------------------------------------------------
__global__ __launch_bounds__(256) void k3_softmax(
    const float* __restrict__ Spart, f16* __restrict__ Sh)
{
  const int row = blockIdx.x * 4 + (threadIdx.x >> 6);  // 2048 rows
  const int lane = threadIdx.x & 63;
  const size_t base = (size_t)row * NI + lane * 4;
  f32x4 v = {0.f, 0.f, 0.f, 0.f};
#pragma unroll
  for (int kt = 0; kt < 8; ++kt) {
    const f32x4 p = *(const f32x4*)(Spart + (size_t)kt * B_ * NI * NI + base);
    v[0] += p[0]; v[1] += p[1]; v[2] += p[2]; v[3] += p[3];
  }
  float m = fmaxf(fmaxf(v[0], v[1]), fmaxf(v[2], v[3]));
#pragma unroll
  for (int d = 1; d < 64; d <<= 1) m = fmaxf(m, __shfl_xor(m, d, 64));
  const float e0 = expf(v[0] - m), e1 = expf(v[1] - m), e2 = expf(v[2] - m), e3 = expf(v[3] - m);
  float s = e0 + e1 + e2 + e3;
#pragma unroll
  for (int d = 1; d < 64; d <<= 1) s += __shfl_xor(s, d, 64);
  const float inv = 1.f / s;
  f16x4 o;
  o[0] = (f16)(e0 * inv); o[1] = (f16)(e1 * inv); o[2] = (f16)(e2 * inv); o[3] = (f16)(e3 * inv);
  *(f16x4*)(Sh + (size_t)row * NI + lane * 4) = o;
}

// ---------------------------------------------------------------------------
// K4 (m97-structure + fused residual): per-batch GEMM
// Y[i][c4] = sum_j Vtt[c4][j]*Sh[i][j] + Vtt[c4][i]. (unchanged)
// ---------------------------------------------------------------------------
__global__ __launch_bounds__(256) void k4_ev(
    const f16* __restrict__ Vtt, const f16* __restrict__ Sh, f16* __restrict__ Y)
{
  __shared__ __align__(16) f16 As[128 * 64];  // [m][k] linear, 16 KB
  __shared__ __align__(16) f16 Bs[128 * 64];  // [n][k] linear, 16 KB
  const int mt = blockIdx.x, nt = blockIdx.y, b = blockIdx.z;
  const int m0 = mt * 128, n0 = nt * 128;
  const int tid = threadIdx.x, wave = tid >> 6, lane = tid & 63;
  const int li = lane & 15, lk = lane >> 4;
  const int wm = wave >> 1, wn = wave & 1;
  const f16* Va  = Vtt + (size_t)b * C4 * NI;
  const f16* Shb = Sh + (size_t)b * NI * NI;

  const int srow = tid >> 3, scol = (tid & 7) * 8;

  f32x4 acc[4][4] = {};

#define K4_STAGE(k0)                                                          \
  {                                                                           \
    _Pragma("unroll")                                                         \
    for (int j = 0; j < 4; ++j) {                                             \
      const int rg = j * 32 + srow;                                           \
      gld16(Va + (size_t)(m0 + rg) * NI + (k0) + scol,                        \
            (char*)As + j * 4096 + wave * 1024);                              \
      gld16(Shb + (size_t)(n0 + rg) * NI + (k0) + scol,                       \
            (char*)Bs + j * 4096 + wave * 1024);                              \
    }                                                                         \
  }

  K4_STAGE(0);
#pragma unroll
  for (int kt = 0; kt < 4; ++kt) {
    __syncthreads();
#pragma unroll
    for (int kh = 0; kh < 2; ++kh) {
      f16x8 af[4], bf[4];
#pragma unroll
      for (int mi = 0; mi < 4; ++mi)
        af[mi] = *(const f16x8*)&As[(wm * 64 + mi * 16 + li) * 64 + kh * 32 + lk * 8];
#pragma unroll
      for (int ni = 0; ni < 4; ++ni)
        bf[ni] = *(const f16x8*)&Bs[(wn * 64 + ni * 16 + li) * 64 + kh * 32 + lk * 8];
#pragma unroll
      for (int mi = 0; mi < 4; ++mi)
#pragma unroll
        for (int ni = 0; ni < 4; ++ni)
          acc[mi][ni] = __builtin_amdgcn_mfma_f32_16x16x32_f16(af[mi], bf[ni], acc[mi][ni], 0, 0, 0);
    }
    __syncthreads();
    if (kt < 3) K4_STAGE((kt + 1) * 64);
  }
#undef K4_STAGE

#pragma unroll
  for (int mi = 0; mi < 4; ++mi)
#pragma unroll
    for (int ni = 0; ni < 4; ++ni) {
      const int i = n0 + wn * 64 + ni * 16 + li;
      const int m = m0 + wm * 64 + mi * 16 + lk * 4;
      const f16* vres = Va + (size_t)m * NI + i;   // Vtt[b][m+r][i]
      f16x4 p;
#pragma unroll
      for (int r = 0; r < 4; ++r)
        p[r] = (f16)(acc[mi][ni][r] + (float)vres[(size_t)r * NI]);
      *(f16x4*)(Y + ((size_t)(b * NI + i)) * C4 + m) = p;
    }
}

// ---------------------------------------------------------------------------
// K5: out[b,o,h,w] = sum_ci w1[o,ci] * Y[b, i(h,w), t(h,w)*32+ci], fp32.
// (unchanged)
// ---------------------------------------------------------------------------
__global__ __launch_bounds__(256) void k5_w1_unpermute(
    const f16* __restrict__ Y, const float* __restrict__ w1, float* __restrict__ out)
{
  __shared__ f16 w1s[32 * 32];
  const int bid = blockIdx.x;
  const int b = bid >> 8, i = bid & 255;
  const int hi = i >> 4, wi = i & 15;
  const int tid = threadIdx.x;
#pragma unroll
  for (int e = 0; e < 4; ++e) w1s[tid + 256 * e] = (f16)w1[tid + 256 * e];
  __syncthreads();

  const int wave = tid >> 6, lane = tid & 63, li = lane & 15, lk = lane >> 4;
  const f16* Yrow = Y + ((size_t)(b * NI + i)) * C4;
  const f16x8 b0 = *(const f16x8*)(&w1s[li * 32 + lk * 8]);         // o = li
  const f16x8 b1 = *(const f16x8*)(&w1s[(16 + li) * 32 + lk * 8]);  // o = 16+li

#pragma unroll
  for (int q = 0; q < 4; ++q) {
    const int tt = wave * 4 + q;
    const f16x8 a = *(const f16x8*)(Yrow + (size_t)(tt * 16 + li) * 32 + lk * 8);
    f32x4 d0 = {}, d1 = {};
    d0 = __builtin_amdgcn_mfma_f32_16x16x32_f16(a, b0, d0, 0, 0, 0);
    d1 = __builtin_amdgcn_mfma_f32_16x16x32_f16(a, b1, d1, 0, 0, 0);
#pragma unroll
    for (int r = 0; r < 4; ++r) {
      const int t = tt * 16 + lk * 4 + r;
      const int dh = dh_of(t), dw = dw_of(t);
      const int h = hi * 16 + dh, w = wi * 16 + dw;
      out[(((size_t)(b * 32 + li)) * 256 + h) * 256 + w] = d0[r];
      out[(((size_t)(b * 32 + 16 + li)) * 256 + h) * 256 + w] = d1[r];
    }
  }
}

// ---------------------------------------------------------------------------
extern "C" void kernel_launch(void* const* d_in, const int* in_sizes, int n_in,
                              void* d_out, int out_size, void* d_ws, size_t ws_size,
                              hipStream_t stream)
{
  const float* x  = (const float*)d_in[0];
  const float* wq = (const float*)d_in[1];
  const float* bq = (const float*)d_in[2];
  const float* wk = (const float*)d_in[3];
  const float* bk = (const float*)d_in[4];
  const float* w1 = (const float*)d_in[5];
  float* out = (float*)d_out;
  char* ws = (char*)d_ws;

  // ws: Qn [0,32M) | Kn [32M,64M) | Vtt [64M,96M) | Spart [96M,112M) | Sh [112M,113M)
  // Y aliases Qn (dead after K2).
  f16*   Qn    = (f16*)(ws);
  f16*   Kn    = (f16*)(ws + 33554432);
  f16*   Vtt   = (f16*)(ws + 67108864);
  float* Spart = (float*)(ws + 100663296);
  f16*   Sh    = (f16*)(ws + 117440512);
  f16*   Y     = Qn;

  k1a_conv<<<1024, 256, 0, stream>>>(x, wq, bq, wk, bk, Qn, Kn, Vtt);
  k2_logits<<<dim3(8, 8, 8), 256, 0, stream>>>(Qn, Kn, Spart);
  k3_softmax<<<512, 256, 0, stream>>>(Spart, Sh);
  k4_ev<<<dim3(64, 2, 8), 256, 0, stream>>>(Vtt, Sh, Y);
  k5_w1_unpermute<<<2048, 256, 0, stream>>>(Y, w1, out);
}